// Round 8
// baseline (225.368 us; speedup 1.0000x reference)
//
#include <hip/hip_runtime.h>
#include <math.h>

#define B 32
#define N 1024
#define W 128
#define R 4
#define EPSC 1e-8f

typedef float f32x4 __attribute__((ext_vector_type(4)));

// ---- ws layout (in floats) ----
#define WS_SUM   0                              // 1 float
#define WS_KSUM  64                             // B*5 softmax denominators
#define WS_BW    256                            // B*16*R*N
#define WS_FW    (WS_BW + B*16*R*N)             // B*R*N
#define WS_ER    (WS_FW + B*R*N)                // B*R*N  exp(cos) read keys
#define WS_EW    (WS_ER + B*R*N)                // B*N    exp(cos*wstr) write key
#define WS_WW    (WS_EW + B*N)                  // B*N

// ---- out offsets (in floats) ----
#define O_RR    0
#define O_MEM   (O_RR + B*R*W)
#define O_LINK  (O_MEM + B*N*W)
#define O_USAGE (O_LINK + B*N*N)
#define O_PREC  (O_USAGE + B*N)
#define O_NRW   (O_PREC + B*N)

#define DOT4(a, bv) ((a).x*(bv).x + (a).y*(bv).y + (a).z*(bv).z + (a).w*(bv).w)

// ===================== K1: cosine scores + exp + partial sums =====================
__global__ void k1_scores(const float* __restrict__ mem,
                          const float* __restrict__ rkeys,
                          const float* __restrict__ wkey,
                          const float* __restrict__ wstr,
                          float* __restrict__ ws) {
    int bx = blockIdx.x;
    int b = bx >> 6;
    int n0 = (bx & 63) << 4;
    int t = threadIdx.x;
    __shared__ float keys[5][W];
    __shared__ float knorm[5];
    __shared__ float epart[5][16];
    for (int idx = t; idx < 5 * W; idx += 256) {
        int r = idx >> 7, w = idx & 127;
        keys[r][w] = (r < 4) ? rkeys[(b * R + r) * W + w] : wkey[b * W + w];
    }
    __syncthreads();
    if (t < 160) {
        int kidx = t >> 5, l = t & 31;
        float s = 0.f;
        #pragma unroll
        for (int c = 0; c < 4; ++c) { float v = keys[kidx][l * 4 + c]; s += v * v; }
        #pragma unroll
        for (int st = 1; st <= 16; st <<= 1) s += __shfl_xor(s, st);
        if (l == 0) knorm[kidx] = sqrtf(s);
    }
    __syncthreads();
    int l16 = t & 15;
    int rloc = t >> 4;          // 0..15
    int n = n0 + rloc;
    const float* mrow = mem + ((size_t)(b * N + n)) * W + l16 * 8;
    float4 a  = *reinterpret_cast<const float4*>(mrow);
    float4 a2 = *reinterpret_cast<const float4*>(mrow + 4);
    float mm = DOT4(a, a) + DOT4(a2, a2);
    float d[5];
    #pragma unroll
    for (int r = 0; r < 5; ++r) {
        float4 k1v = *reinterpret_cast<const float4*>(&keys[r][l16 * 8]);
        float4 k2v = *reinterpret_cast<const float4*>(&keys[r][l16 * 8 + 4]);
        d[r] = DOT4(a, k1v) + DOT4(a2, k2v);
    }
    #pragma unroll
    for (int st = 1; st <= 8; st <<= 1) {
        mm += __shfl_xor(mm, st);
        #pragma unroll
        for (int r = 0; r < 5; ++r) d[r] += __shfl_xor(d[r], st);
    }
    if (l16 == 0) {
        float mn = sqrtf(mm);
        float e[5];
        #pragma unroll
        for (int r = 0; r < 4; ++r) {
            float c = d[r] / fmaxf(knorm[r] * mn, EPSC);
            e[r] = expf(c);
            ws[WS_ER + (b * R + r) * N + n] = e[r];
        }
        float cw = d[4] / fmaxf(knorm[4] * mn, EPSC);
        e[4] = expf(cw * wstr[b]);
        ws[WS_EW + b * N + n] = e[4];
        #pragma unroll
        for (int q = 0; q < 5; ++q) epart[q][rloc] = e[q];
    }
    __syncthreads();
    if (t < 80) {
        int q = t >> 4, i = t & 15;
        float v = epart[q][i];
        #pragma unroll
        for (int st = 1; st <= 8; st <<= 1) v += __shfl_xor(v, st);
        if (i == 0) atomicAdd(&ws[WS_KSUM + b * 5 + q], v);
    }
}

// ===================== K3: ww scan + single pass over L (v5) =====================
// grid B*16 (64-row strips), block 256. Inline ww scan (strip 0 publishes).
// Barrier-free main loop: wave-private fw reduce (each wave reduces its own
// 64 scratch rows), 2-deep double-buffered batch prefetch, NT link stores.
__global__ __launch_bounds__(256, 2) void k3_link(
                        const float* __restrict__ L,
                        const float* __restrict__ rw,
                        const float* __restrict__ prec,
                        const float* __restrict__ usage,
                        const float* __restrict__ agate,
                        const float* __restrict__ wgate,
                        float* __restrict__ ws,
                        float* __restrict__ out) {
    int bx = blockIdx.x;
    int b = bx >> 4;
    int strip = bx & 15;
    int i0 = strip << 6;
    int t = threadIdx.x;
    int lane = t & 63, wv = t >> 6;
    __shared__ float scratch[256][36];   // per-wave region: rows [64w, 64w+63]
    __shared__ float ww_l[N];
    __shared__ float rw_row[R][64];
    __shared__ float fwpart[4][64][4];   // per-wave fw partials
    __shared__ float wpart[4];
    __shared__ float red[4];

    int j0 = 4 * t;

    // ---- inline ww computation ----
    float4 u4 = *reinterpret_cast<const float4*>(usage + b * N + j0);
    float4 e4 = *reinterpret_cast<const float4*>(ws + WS_EW + b * N + j0);
    float ksw = ws[WS_KSUM + b * 5 + 4];
    float p = u4.x * u4.y * u4.z * u4.w;
    float incl = p;
    #pragma unroll
    for (int s = 1; s <= 32; s <<= 1) {
        float up = __shfl_up(incl, s);
        if (lane >= s) incl *= up;
    }
    if (lane == 63) wpart[wv] = incl;
    // independent: stage rw rows for this strip
    for (int idx = t; idx < R * 64; idx += 256) {
        int r = idx >> 6, i = idx & 63;
        rw_row[r][i] = rw[(b * R + r) * N + i0 + i];
    }
    __syncthreads();
    float woff = 1.f;
    #pragma unroll
    for (int w = 0; w < 3; ++w) if (w < wv) woff *= wpart[w];
    float eu = __shfl_up(incl, 1);
    float excl = (lane == 0 ? 1.f : eu) * woff;
    float ag = agate[b], wg = wgate[b];
    float invk = 1.f / ksw;
    float e0 = excl, e1 = e0 * u4.x, e2 = e1 * u4.y, e3 = e2 * u4.z;
    float wc0 = e4.x * invk, wc1 = e4.y * invk, wc2 = e4.z * invk, wc3 = e4.w * invk;
    float4 wwj;
    wwj.x = (ag * ((1.f - u4.x) * e0 - wc0) + wc0) * wg;
    wwj.y = (ag * ((1.f - u4.y) * e1 - wc1) + wc1) * wg;
    wwj.z = (ag * ((1.f - u4.z) * e2 - wc2) + wc2) * wg;
    wwj.w = (ag * ((1.f - u4.w) * e3 - wc3) + wc3) * wg;
    *reinterpret_cast<float4*>(&ww_l[j0]) = wwj;
    float lsum = wwj.x + wwj.y + wwj.z + wwj.w;
    #pragma unroll
    for (int s = 1; s <= 32; s <<= 1) lsum += __shfl_xor(lsum, s);
    if (lane == 0) red[wv] = lsum;
    if (strip == 0)
        *reinterpret_cast<float4*>(ws + WS_WW + b * N + j0) = wwj;  // publish for k4

    // ---- main-loop setup + batch-0 prefetch (before the barrier) ----
    float4 pj  = *reinterpret_cast<const float4*>(prec + b * N + j0);
    float4 rwj[R];
    #pragma unroll
    for (int r = 0; r < R; ++r)
        rwj[r] = *reinterpret_cast<const float4*>(rw + (b * R + r) * N + j0);
    float4 bwa[R];
    #pragma unroll
    for (int r = 0; r < R; ++r) bwa[r] = make_float4(0.f, 0.f, 0.f, 0.f);

    const float* Lr = L + ((size_t)(b * N + i0)) * N + j0;
    float* Or = out + O_LINK + ((size_t)(b * N + i0)) * N + j0;

    int wbase = t & 192;          // wave's scratch base row
    int half32 = (t & 1) << 5;    // reducer half
    int oidx = (t & 63) >> 1;     // output column 0..31 (= k*4 + r)

    float4 va[8], vb[8];
#define LOADB(dst, bat)                                                        \
    {                                                                          \
        _Pragma("unroll")                                                      \
        for (int k = 0; k < 8; ++k)                                            \
            dst[k] = *reinterpret_cast<const float4*>(                         \
                Lr + (size_t)((bat) * 8 + k) * N);                             \
    }

    LOADB(va, 0);
    __syncthreads();
    if (t == 0 && strip == 0)
        atomicAdd(&ws[WS_SUM], red[0] + red[1] + red[2] + red[3]);

#define PROCESS(vv, bat)                                                       \
    {                                                                          \
        _Pragma("unroll")                                                      \
        for (int k = 0; k < 8; ++k) {                                          \
            int row = (bat) * 8 + k;                                           \
            float wi = ww_l[i0 + row];                                         \
            float c = 1.f - wi;                                                \
            f32x4 o;                                                           \
            o.x = (c - wwj.x) * vv[k].x + wi * pj.x;                           \
            o.y = (c - wwj.y) * vv[k].y + wi * pj.y;                           \
            o.z = (c - wwj.z) * vv[k].z + wi * pj.z;                           \
            o.w = (c - wwj.w) * vv[k].w + wi * pj.w;                           \
            __builtin_nontemporal_store(o,                                     \
                reinterpret_cast<f32x4*>(Or + (size_t)row * N));               \
            float4 f;                                                          \
            f.x = DOT4(vv[k], rwj[0]); f.y = DOT4(vv[k], rwj[1]);              \
            f.z = DOT4(vv[k], rwj[2]); f.w = DOT4(vv[k], rwj[3]);              \
            *reinterpret_cast<float4*>(&scratch[t][k * 4]) = f;                \
            _Pragma("unroll")                                                  \
            for (int r = 0; r < R; ++r) {                                      \
                float q = rw_row[r][row];                                      \
                bwa[r].x += q * vv[k].x; bwa[r].y += q * vv[k].y;              \
                bwa[r].z += q * vv[k].z; bwa[r].w += q * vv[k].w;              \
            }                                                                  \
        }                                                                      \
        float s_ = 0.f;                                                        \
        _Pragma("unroll")                                                      \
        for (int m = 0; m < 32; ++m)                                           \
            s_ += scratch[wbase + half32 + m][oidx];                           \
        s_ += __shfl_xor(s_, 1);                                               \
        if (!(t & 1)) fwpart[wv][(bat) * 8 + (oidx >> 2)][oidx & 3] = s_;      \
    }

    LOADB(vb, 1); PROCESS(va, 0);
    LOADB(va, 2); PROCESS(vb, 1);
    LOADB(vb, 3); PROCESS(va, 2);
    LOADB(va, 4); PROCESS(vb, 3);
    LOADB(vb, 5); PROCESS(va, 4);
    LOADB(va, 6); PROCESS(vb, 5);
    LOADB(vb, 7); PROCESS(va, 6);
    PROCESS(vb, 7);

    __syncthreads();

    // fw: cross-wave reduce of 4 partials, store final
    {
        int row = t >> 2, r = t & 3;
        float s = fwpart[0][row][r] + fwpart[1][row][r]
                + fwpart[2][row][r] + fwpart[3][row][r];
        ws[WS_FW + (b * R + r) * N + i0 + row] = s;
    }

    // bw: per-strip partials to ws (no global atomics)
    float* bwout = ws + WS_BW + (size_t)(b * 16 + strip) * R * N;
    #pragma unroll
    for (int r = 0; r < R; ++r)
        *reinterpret_cast<float4*>(bwout + r * N + j0) = bwa[r];
#undef LOADB
#undef PROCESS
}

// ===================== K4: finalize =====================
// grid B*16 (64-row chunks), block 256.
__global__ void k4_final(const float* __restrict__ mem,
                         const float* __restrict__ usage,
                         const float* __restrict__ prec,
                         const float* __restrict__ rmodes,
                         const float* __restrict__ rstr,
                         const float* __restrict__ fgates,
                         const float* __restrict__ ev,
                         const float* __restrict__ wvec,
                         float* __restrict__ ws,
                         float* __restrict__ out) {
    int bx = blockIdx.x;
    int b = bx >> 4;
    int n0 = (bx & 15) << 6;
    int t = threadIdx.x;
    __shared__ float nrw[R][64];
    __shared__ float wwl[64];
    __shared__ float rrl[2][R][W];

    // phase 1: new_rw (256 = R*64 work items); content weight finished inline
    {
        int r = t >> 6, nl = t & 63, n = n0 + nl;
        float bs = 0.f;
        #pragma unroll
        for (int tile = 0; tile < 16; ++tile)
            bs += ws[WS_BW + ((size_t)(b * 16 + tile) * R + r) * N + n];
        float fwv = ws[WS_FW + (b * R + r) * N + n];
        float cv  = ws[WS_ER + (b * R + r) * N + n] / ws[WS_KSUM + b * 5 + r]
                    * rstr[b * R + r];
        float m0 = rmodes[(b * R + r) * 3 + 0];
        float m1 = rmodes[(b * R + r) * 3 + 1];
        float m2 = rmodes[(b * R + r) * 3 + 2];
        float v = fwv * m0 + bs * m1 + cv * m2;
        out[O_NRW + (b * R + r) * N + n] = v;
        nrw[r][nl] = v;
    }
    __syncthreads();

    // phase 2: usage_new, precedence_new
    if (t < 64) {
        int n = n0 + t;
        float ret = 1.f;
        #pragma unroll
        for (int r = 0; r < R; ++r) ret *= (1.f - fgates[b * R + r] * nrw[r][t]);
        float u = usage[b * N + n];
        float w = ws[WS_WW + b * N + n];
        out[O_USAGE + b * N + n] = (u + w - u * w) * ret;
        float S = ws[WS_SUM];
        out[O_PREC + b * N + n] = (1.f - S) * prec[b * N + n] + w;
        wwl[t] = w;
    }
    __syncthreads();

    // phase 3: memory_new + read_result partial
    int wi = t & 127, half = t >> 7;
    float er = ev[b * W + wi], wvv = wvec[b * W + wi];
    float acc[R] = {0.f, 0.f, 0.f, 0.f};
    for (int k = 0; k < 32; ++k) {
        int nl = half * 32 + k;
        int n = n0 + nl;
        size_t off = ((size_t)(b * N + n)) * W + wi;
        float m = mem[off];
        float wn = wwl[nl];
        out[O_MEM + off] = m * (1.f - wn * er) + wn * wvv;
        #pragma unroll
        for (int r = 0; r < R; ++r) acc[r] += nrw[r][nl] * m;
    }
    #pragma unroll
    for (int r = 0; r < R; ++r) rrl[half][r][wi] = acc[r];
    __syncthreads();
    for (int idx = t; idx < R * W; idx += 256) {
        int r = idx >> 7, w2 = idx & 127;
        atomicAdd(&out[O_RR + (b * R + r) * W + w2], rrl[0][r][w2] + rrl[1][r][w2]);
    }
}

extern "C" void kernel_launch(void* const* d_in, const int* in_sizes, int n_in,
                              void* d_out, int out_size, void* d_ws, size_t ws_size,
                              hipStream_t stream) {
    const float* mem    = (const float*)d_in[0];
    const float* L      = (const float*)d_in[1];
    const float* usage  = (const float*)d_in[2];
    const float* prec   = (const float*)d_in[3];
    const float* rw     = (const float*)d_in[4];
    const float* rkeys  = (const float*)d_in[5];
    const float* rstr   = (const float*)d_in[6];
    const float* rmodes = (const float*)d_in[7];
    const float* wkey   = (const float*)d_in[8];
    const float* wstr   = (const float*)d_in[9];
    const float* ag     = (const float*)d_in[10];
    const float* wg     = (const float*)d_in[11];
    const float* wv     = (const float*)d_in[12];
    const float* ev     = (const float*)d_in[13];
    const float* fg     = (const float*)d_in[14];
    float* out = (float*)d_out;
    float* ws  = (float*)d_ws;

    (void)hipMemsetAsync(ws, 0, 1024, stream);                               // sum_ww + ksum
    (void)hipMemsetAsync(out, 0, (size_t)B * R * W * sizeof(float), stream); // read_result

    k1_scores<<<B * 64, 256, 0, stream>>>(mem, rkeys, wkey, wstr, ws);
    k3_link<<<B * 16, 256, 0, stream>>>(L, rw, prec, usage, ag, wg, ws, out);
    k4_final<<<B * 16, 256, 0, stream>>>(mem, usage, prec, rmodes, rstr, fg, ev, wv, ws, out);
}

// Round 9
// 214.768 us; speedup vs baseline: 1.0494x; 1.0494x over previous
//
#include <hip/hip_runtime.h>
#include <math.h>

#define B 32
#define N 1024
#define W 128
#define R 4
#define EPSC 1e-8f

typedef float f32x4 __attribute__((ext_vector_type(4)));

// ---- ws layout (in floats) ----
#define WS_SUM   0                              // 1 float
#define WS_KSUM  64                             // B*5 softmax denominators
#define WS_BW    256                            // B*16*R*N
#define WS_FW    (WS_BW + B*16*R*N)             // B*R*N
#define WS_ER    (WS_FW + B*R*N)                // B*R*N  exp(cos) read keys
#define WS_EW    (WS_ER + B*R*N)                // B*N    exp(cos*wstr) write key
#define WS_WW    (WS_EW + B*N)                  // B*N

// ---- out offsets (in floats) ----
#define O_RR    0
#define O_MEM   (O_RR + B*R*W)
#define O_LINK  (O_MEM + B*N*W)
#define O_USAGE (O_LINK + B*N*N)
#define O_PREC  (O_USAGE + B*N)
#define O_NRW   (O_PREC + B*N)

#define DOT4(a, bv) ((a).x*(bv).x + (a).y*(bv).y + (a).z*(bv).z + (a).w*(bv).w)

// ===================== K1: cosine scores + exp + partial sums =====================
__global__ void k1_scores(const float* __restrict__ mem,
                          const float* __restrict__ rkeys,
                          const float* __restrict__ wkey,
                          const float* __restrict__ wstr,
                          float* __restrict__ ws) {
    int bx = blockIdx.x;
    int b = bx >> 6;
    int n0 = (bx & 63) << 4;
    int t = threadIdx.x;
    __shared__ float keys[5][W];
    __shared__ float knorm[5];
    __shared__ float epart[5][16];
    for (int idx = t; idx < 5 * W; idx += 256) {
        int r = idx >> 7, w = idx & 127;
        keys[r][w] = (r < 4) ? rkeys[(b * R + r) * W + w] : wkey[b * W + w];
    }
    __syncthreads();
    if (t < 160) {
        int kidx = t >> 5, l = t & 31;
        float s = 0.f;
        #pragma unroll
        for (int c = 0; c < 4; ++c) { float v = keys[kidx][l * 4 + c]; s += v * v; }
        #pragma unroll
        for (int st = 1; st <= 16; st <<= 1) s += __shfl_xor(s, st);
        if (l == 0) knorm[kidx] = sqrtf(s);
    }
    __syncthreads();
    int l16 = t & 15;
    int rloc = t >> 4;          // 0..15
    int n = n0 + rloc;
    const float* mrow = mem + ((size_t)(b * N + n)) * W + l16 * 8;
    float4 a  = *reinterpret_cast<const float4*>(mrow);
    float4 a2 = *reinterpret_cast<const float4*>(mrow + 4);
    float mm = DOT4(a, a) + DOT4(a2, a2);
    float d[5];
    #pragma unroll
    for (int r = 0; r < 5; ++r) {
        float4 k1v = *reinterpret_cast<const float4*>(&keys[r][l16 * 8]);
        float4 k2v = *reinterpret_cast<const float4*>(&keys[r][l16 * 8 + 4]);
        d[r] = DOT4(a, k1v) + DOT4(a2, k2v);
    }
    #pragma unroll
    for (int st = 1; st <= 8; st <<= 1) {
        mm += __shfl_xor(mm, st);
        #pragma unroll
        for (int r = 0; r < 5; ++r) d[r] += __shfl_xor(d[r], st);
    }
    if (l16 == 0) {
        float mn = sqrtf(mm);
        float e[5];
        #pragma unroll
        for (int r = 0; r < 4; ++r) {
            float c = d[r] / fmaxf(knorm[r] * mn, EPSC);
            e[r] = expf(c);
            ws[WS_ER + (b * R + r) * N + n] = e[r];
        }
        float cw = d[4] / fmaxf(knorm[4] * mn, EPSC);
        e[4] = expf(cw * wstr[b]);
        ws[WS_EW + b * N + n] = e[4];
        #pragma unroll
        for (int q = 0; q < 5; ++q) epart[q][rloc] = e[q];
    }
    __syncthreads();
    if (t < 80) {
        int q = t >> 4, i = t & 15;
        float v = epart[q][i];
        #pragma unroll
        for (int st = 1; st <= 8; st <<= 1) v += __shfl_xor(v, st);
        if (i == 0) atomicAdd(&ws[WS_KSUM + b * 5 + q], v);
    }
}

// ===================== K3: ww scan + single pass over L (v6) =====================
// grid B*16 (64-row strips), block 256. Inline ww scan (strip 0 publishes).
// Barrier-free main loop: single v[8] buffer (no spills); per batch:
// compute+store -> issue next batch's loads -> wave-private fw reduce.
__global__ __launch_bounds__(256, 2) void k3_link(
                        const float* __restrict__ L,
                        const float* __restrict__ rw,
                        const float* __restrict__ prec,
                        const float* __restrict__ usage,
                        const float* __restrict__ agate,
                        const float* __restrict__ wgate,
                        float* __restrict__ ws,
                        float* __restrict__ out) {
    int bx = blockIdx.x;
    int b = bx >> 4;
    int strip = bx & 15;
    int i0 = strip << 6;
    int t = threadIdx.x;
    int lane = t & 63, wv = t >> 6;
    __shared__ float scratch[256][36];   // per-wave region: rows [64w, 64w+63]
    __shared__ float ww_l[N];
    __shared__ float rw_row[R][64];
    __shared__ float fwpart[4][64][4];   // per-wave fw partials
    __shared__ float wpart[4];
    __shared__ float red[4];

    int j0 = 4 * t;

    // ---- inline ww computation ----
    float4 u4 = *reinterpret_cast<const float4*>(usage + b * N + j0);
    float4 e4 = *reinterpret_cast<const float4*>(ws + WS_EW + b * N + j0);
    float ksw = ws[WS_KSUM + b * 5 + 4];
    float p = u4.x * u4.y * u4.z * u4.w;
    float incl = p;
    #pragma unroll
    for (int s = 1; s <= 32; s <<= 1) {
        float up = __shfl_up(incl, s);
        if (lane >= s) incl *= up;
    }
    if (lane == 63) wpart[wv] = incl;
    // independent: stage rw rows for this strip
    for (int idx = t; idx < R * 64; idx += 256) {
        int r = idx >> 6, i = idx & 63;
        rw_row[r][i] = rw[(b * R + r) * N + i0 + i];
    }
    __syncthreads();
    float woff = 1.f;
    #pragma unroll
    for (int w = 0; w < 3; ++w) if (w < wv) woff *= wpart[w];
    float eu = __shfl_up(incl, 1);
    float excl = (lane == 0 ? 1.f : eu) * woff;
    float ag = agate[b], wg = wgate[b];
    float invk = 1.f / ksw;
    float e0 = excl, e1 = e0 * u4.x, e2 = e1 * u4.y, e3 = e2 * u4.z;
    float wc0 = e4.x * invk, wc1 = e4.y * invk, wc2 = e4.z * invk, wc3 = e4.w * invk;
    float4 wwj;
    wwj.x = (ag * ((1.f - u4.x) * e0 - wc0) + wc0) * wg;
    wwj.y = (ag * ((1.f - u4.y) * e1 - wc1) + wc1) * wg;
    wwj.z = (ag * ((1.f - u4.z) * e2 - wc2) + wc2) * wg;
    wwj.w = (ag * ((1.f - u4.w) * e3 - wc3) + wc3) * wg;
    *reinterpret_cast<float4*>(&ww_l[j0]) = wwj;
    float lsum = wwj.x + wwj.y + wwj.z + wwj.w;
    #pragma unroll
    for (int s = 1; s <= 32; s <<= 1) lsum += __shfl_xor(lsum, s);
    if (lane == 0) red[wv] = lsum;
    if (strip == 0)
        *reinterpret_cast<float4*>(ws + WS_WW + b * N + j0) = wwj;  // publish for k4

    // ---- main-loop setup ----
    float4 pj  = *reinterpret_cast<const float4*>(prec + b * N + j0);
    float4 rwj[R];
    #pragma unroll
    for (int r = 0; r < R; ++r)
        rwj[r] = *reinterpret_cast<const float4*>(rw + (b * R + r) * N + j0);
    float4 bwa[R];
    #pragma unroll
    for (int r = 0; r < R; ++r) bwa[r] = make_float4(0.f, 0.f, 0.f, 0.f);

    const float* Lr = L + ((size_t)(b * N + i0)) * N + j0;
    float* Or = out + O_LINK + ((size_t)(b * N + i0)) * N + j0;

    int wbase = t & 192;          // wave's scratch base row
    int half32 = (t & 1) << 5;    // reducer half
    int oidx = (t & 63) >> 1;     // output column 0..31 (= k*4 + r)

    float4 v[8];
#define LOADB(bat)                                                             \
    {                                                                          \
        _Pragma("unroll")                                                      \
        for (int k = 0; k < 8; ++k)                                            \
            v[k] = *reinterpret_cast<const float4*>(                           \
                Lr + (size_t)((bat) * 8 + k) * N);                             \
    }

    LOADB(0);
    __syncthreads();
    if (t == 0 && strip == 0)
        atomicAdd(&ws[WS_SUM], red[0] + red[1] + red[2] + red[3]);

#define COMPUTE(bat)                                                           \
    {                                                                          \
        _Pragma("unroll")                                                      \
        for (int k = 0; k < 8; ++k) {                                          \
            int row = (bat) * 8 + k;                                           \
            float wi = ww_l[i0 + row];                                         \
            float c = 1.f - wi;                                                \
            f32x4 o;                                                           \
            o.x = (c - wwj.x) * v[k].x + wi * pj.x;                            \
            o.y = (c - wwj.y) * v[k].y + wi * pj.y;                            \
            o.z = (c - wwj.z) * v[k].z + wi * pj.z;                            \
            o.w = (c - wwj.w) * v[k].w + wi * pj.w;                            \
            __builtin_nontemporal_store(o,                                     \
                reinterpret_cast<f32x4*>(Or + (size_t)row * N));               \
            float4 f;                                                          \
            f.x = DOT4(v[k], rwj[0]); f.y = DOT4(v[k], rwj[1]);                \
            f.z = DOT4(v[k], rwj[2]); f.w = DOT4(v[k], rwj[3]);                \
            *reinterpret_cast<float4*>(&scratch[t][k * 4]) = f;                \
            _Pragma("unroll")                                                  \
            for (int r = 0; r < R; ++r) {                                      \
                float q = rw_row[r][row];                                      \
                bwa[r].x += q * v[k].x; bwa[r].y += q * v[k].y;                \
                bwa[r].z += q * v[k].z; bwa[r].w += q * v[k].w;                \
            }                                                                  \
        }                                                                      \
    }

#define REDUCE(bat)                                                            \
    {                                                                          \
        float s_ = 0.f;                                                        \
        _Pragma("unroll")                                                      \
        for (int m = 0; m < 32; ++m)                                           \
            s_ += scratch[wbase + half32 + m][oidx];                           \
        s_ += __shfl_xor(s_, 1);                                               \
        if (!(t & 1)) fwpart[wv][(bat) * 8 + (oidx >> 2)][oidx & 3] = s_;      \
    }

    COMPUTE(0); LOADB(1); REDUCE(0);
    COMPUTE(1); LOADB(2); REDUCE(1);
    COMPUTE(2); LOADB(3); REDUCE(2);
    COMPUTE(3); LOADB(4); REDUCE(3);
    COMPUTE(4); LOADB(5); REDUCE(4);
    COMPUTE(5); LOADB(6); REDUCE(5);
    COMPUTE(6); LOADB(7); REDUCE(6);
    COMPUTE(7); REDUCE(7);

    __syncthreads();

    // fw: cross-wave reduce of 4 partials, store final
    {
        int row = t >> 2, r = t & 3;
        float s = fwpart[0][row][r] + fwpart[1][row][r]
                + fwpart[2][row][r] + fwpart[3][row][r];
        ws[WS_FW + (b * R + r) * N + i0 + row] = s;
    }

    // bw: per-strip partials to ws (no global atomics)
    float* bwout = ws + WS_BW + (size_t)(b * 16 + strip) * R * N;
    #pragma unroll
    for (int r = 0; r < R; ++r)
        *reinterpret_cast<float4*>(bwout + r * N + j0) = bwa[r];
#undef LOADB
#undef COMPUTE
#undef REDUCE
}

// ===================== K4: finalize =====================
// grid B*16 (64-row chunks), block 256.
__global__ void k4_final(const float* __restrict__ mem,
                         const float* __restrict__ usage,
                         const float* __restrict__ prec,
                         const float* __restrict__ rmodes,
                         const float* __restrict__ rstr,
                         const float* __restrict__ fgates,
                         const float* __restrict__ ev,
                         const float* __restrict__ wvec,
                         float* __restrict__ ws,
                         float* __restrict__ out) {
    int bx = blockIdx.x;
    int b = bx >> 4;
    int n0 = (bx & 15) << 6;
    int t = threadIdx.x;
    __shared__ float nrw[R][64];
    __shared__ float wwl[64];
    __shared__ float rrl[2][R][W];

    // phase 1: new_rw (256 = R*64 work items); content weight finished inline
    {
        int r = t >> 6, nl = t & 63, n = n0 + nl;
        float bs = 0.f;
        #pragma unroll
        for (int tile = 0; tile < 16; ++tile)
            bs += ws[WS_BW + ((size_t)(b * 16 + tile) * R + r) * N + n];
        float fwv = ws[WS_FW + (b * R + r) * N + n];
        float cv  = ws[WS_ER + (b * R + r) * N + n] / ws[WS_KSUM + b * 5 + r]
                    * rstr[b * R + r];
        float m0 = rmodes[(b * R + r) * 3 + 0];
        float m1 = rmodes[(b * R + r) * 3 + 1];
        float m2 = rmodes[(b * R + r) * 3 + 2];
        float v = fwv * m0 + bs * m1 + cv * m2;
        out[O_NRW + (b * R + r) * N + n] = v;
        nrw[r][nl] = v;
    }
    __syncthreads();

    // phase 2: usage_new, precedence_new
    if (t < 64) {
        int n = n0 + t;
        float ret = 1.f;
        #pragma unroll
        for (int r = 0; r < R; ++r) ret *= (1.f - fgates[b * R + r] * nrw[r][t]);
        float u = usage[b * N + n];
        float w = ws[WS_WW + b * N + n];
        out[O_USAGE + b * N + n] = (u + w - u * w) * ret;
        float S = ws[WS_SUM];
        out[O_PREC + b * N + n] = (1.f - S) * prec[b * N + n] + w;
        wwl[t] = w;
    }
    __syncthreads();

    // phase 3: memory_new + read_result partial
    int wi = t & 127, half = t >> 7;
    float er = ev[b * W + wi], wvv = wvec[b * W + wi];
    float acc[R] = {0.f, 0.f, 0.f, 0.f};
    for (int k = 0; k < 32; ++k) {
        int nl = half * 32 + k;
        int n = n0 + nl;
        size_t off = ((size_t)(b * N + n)) * W + wi;
        float m = mem[off];
        float wn = wwl[nl];
        out[O_MEM + off] = m * (1.f - wn * er) + wn * wvv;
        #pragma unroll
        for (int r = 0; r < R; ++r) acc[r] += nrw[r][nl] * m;
    }
    #pragma unroll
    for (int r = 0; r < R; ++r) rrl[half][r][wi] = acc[r];
    __syncthreads();
    for (int idx = t; idx < R * W; idx += 256) {
        int r = idx >> 7, w2 = idx & 127;
        atomicAdd(&out[O_RR + (b * R + r) * W + w2], rrl[0][r][w2] + rrl[1][r][w2]);
    }
}

extern "C" void kernel_launch(void* const* d_in, const int* in_sizes, int n_in,
                              void* d_out, int out_size, void* d_ws, size_t ws_size,
                              hipStream_t stream) {
    const float* mem    = (const float*)d_in[0];
    const float* L      = (const float*)d_in[1];
    const float* usage  = (const float*)d_in[2];
    const float* prec   = (const float*)d_in[3];
    const float* rw     = (const float*)d_in[4];
    const float* rkeys  = (const float*)d_in[5];
    const float* rstr   = (const float*)d_in[6];
    const float* rmodes = (const float*)d_in[7];
    const float* wkey   = (const float*)d_in[8];
    const float* wstr   = (const float*)d_in[9];
    const float* ag     = (const float*)d_in[10];
    const float* wg     = (const float*)d_in[11];
    const float* wv     = (const float*)d_in[12];
    const float* ev     = (const float*)d_in[13];
    const float* fg     = (const float*)d_in[14];
    float* out = (float*)d_out;
    float* ws  = (float*)d_ws;

    (void)hipMemsetAsync(ws, 0, 1024, stream);                               // sum_ww + ksum
    (void)hipMemsetAsync(out, 0, (size_t)B * R * W * sizeof(float), stream); // read_result

    k1_scores<<<B * 64, 256, 0, stream>>>(mem, rkeys, wkey, wstr, ws);
    k3_link<<<B * 16, 256, 0, stream>>>(L, rw, prec, usage, ag, wg, ws, out);
    k4_final<<<B * 16, 256, 0, stream>>>(mem, usage, prec, rmodes, rstr, fg, ev, wv, ws, out);
}